// Round 11
// baseline (176.683 us; speedup 1.0000x reference)
//
#include <hip/hip_runtime.h>
#include <stdint.h>

typedef unsigned short u16;
typedef __bf16 bf16x8 __attribute__((ext_vector_type(8)));
typedef __bf16 bf16x4 __attribute__((ext_vector_type(4)));
typedef short s16x4 __attribute__((ext_vector_type(4)));
typedef float f32x4 __attribute__((ext_vector_type(4)));

#define MFMA16(a,b,c) __builtin_amdgcn_mfma_f32_16x16x32_bf16((a),(b),(c),0,0,0)

// K=16 MFMA: D = A(16x16) * B(16x16) + C. B-operand layout (col=l15, k=g*4+j)
// matches the 16x16 C/D layout (col=l15, row=g*4+r) -> S^T regs feed PV directly.
__device__ __forceinline__ f32x4 mfma_k16(bf16x4 a, bf16x4 b, f32x4 c){
#if __has_builtin(__builtin_amdgcn_mfma_f32_16x16x16_bf16)
  return __builtin_amdgcn_mfma_f32_16x16x16_bf16(a, b, c, 0, 0, 0);
#elif __has_builtin(__builtin_amdgcn_mfma_f32_16x16x16bf16_1k)
  s16x4 ai, bi;
  __builtin_memcpy(&ai, &a, 8);
  __builtin_memcpy(&bi, &b, 8);
  return __builtin_amdgcn_mfma_f32_16x16x16bf16_1k(ai, bi, c, 0, 0, 0);
#else
  asm("v_mfma_f32_16x16x16_bf16 %0, %1, %2, %0" : "+v"(c) : "v"(a), "v"(b));
  return c;
#endif
}

__device__ __forceinline__ bf16x4 pack4(float a, float b, float c, float d){
  bf16x4 r; r[0]=(__bf16)a; r[1]=(__bf16)b; r[2]=(__bf16)c; r[3]=(__bf16)d; return r;
}
__device__ __forceinline__ bf16x8 pack8(float4 a, float4 b){
  bf16x8 r;
  r[0]=(__bf16)a.x; r[1]=(__bf16)a.y; r[2]=(__bf16)a.z; r[3]=(__bf16)a.w;
  r[4]=(__bf16)b.x; r[5]=(__bf16)b.y; r[6]=(__bf16)b.z; r[7]=(__bf16)b.w;
  return r;
}

__device__ __forceinline__ void gl2lds16(const void* g, void* l){
  __builtin_amdgcn_global_load_lds(
      (const __attribute__((address_space(1))) unsigned int*)g,
      (__attribute__((address_space(3))) unsigned int*)l, 16, 0, 0);
}

// Read one bf16x8 MFMA fragment from a [rows][64-elem] XOR-swizzled LDS tile.
// Physical granule slot = logical_granule ^ (row & 7)  (16B granules, 8/row).
__device__ __forceinline__ bf16x8 ldsfrag(const u16* base, int row, int gr){
  return *(const bf16x8*)(base + row * 64 + ((gr ^ (row & 7)) << 3));
}
// b64 variant: granule gr, half h (0/1 -> 4-elem offset).
__device__ __forceinline__ bf16x4 ldsfrag64(const u16* base, int row, int gr, int h){
  return *(const bf16x4*)(base + row * 64 + ((gr ^ (row & 7)) << 3) + (h << 2));
}

// ---------------------------------------------------------------------------
// GEMM core: C[M,N] = A[M,K] @ Bt[N,K]^T, fp32 accumulate, double-buffered LDS.
// Block = 256 thr (4 waves, 2x2), tile 128 x BN, BK=64.
// AF32: A is fp32 in global; reg-staged (load f32 early -> cvt -> ds_write
// after compute, T14 pattern). Fuses the bf16 conversion into the GEMM.
// !AF32: A is bf16; async global_load_lds staging.
// mode 0: bf16 C [row*N+col], scaled by oscale
// mode 1: bf16 C transposed-V layout:  [((b*16+h)*64+e)*2048 + l], packed x4
// mode 4: bf16 C + bias[col]
// ---------------------------------------------------------------------------
template<int BN, bool AF32>
__device__ __forceinline__ void gemm_core(const void* __restrict__ Araw,
                                          const u16* __restrict__ Bt,
                                          int N, int K, int mode,
                                          void* __restrict__ Cout,
                                          const float* __restrict__ bias,
                                          float oscale)
{
  constexpr int NF = BN / 32;          // B-frags per wave (wave covers BN/2 cols)
  __shared__ u16 Al[2][128 * 64];
  __shared__ u16 Bl[2][BN * 64];
  const int tid  = threadIdx.x;
  const int lane = tid & 63;
  const int w    = tid >> 6;
  const int wr   = w >> 1, wc = w & 1;
  const int l15  = lane & 15, g = lane >> 4;
  const int rowBase = blockIdx.y << 7;
  const int colBase = blockIdx.x * BN;

  // staging: thread t handles row (i*32 + t/8), granule t%8, pre-swizzled col
  const int srow = tid >> 3;                          // 0..31
  const int swz  = ((tid & 7) ^ (srow & 7)) << 3;     // element offset in row
  const u16*   Ag  = AF32 ? nullptr : (const u16*)Araw + (size_t)(rowBase + srow) * K + swz;
  const float* Agf = AF32 ? (const float*)Araw + (size_t)(rowBase + srow) * K + swz : nullptr;
  const u16*   Bg  = Bt + (size_t)(colBase + srow) * K + swz;

  f32x4 acc[4][NF];
#pragma unroll
  for (int m = 0; m < 4; ++m)
#pragma unroll
    for (int n = 0; n < NF; ++n) acc[m][n] = f32x4{0.f, 0.f, 0.f, 0.f};

  float4 ar[4][2];                     // in-flight f32 A granules (AF32 path)
  auto loadA = [&](int k0) {
    if (AF32) {
#pragma unroll
      for (int i = 0; i < 4; ++i) {
        const float* p = Agf + (size_t)(i * 32) * K + k0;
        ar[i][0] = *(const float4*)p;
        ar[i][1] = *(const float4*)(p + 4);
      }
    }
  };
  auto writeA = [&](int buf) {         // AF32: cvt + ds_write (after compute)
#pragma unroll
    for (int i = 0; i < 4; ++i)
      *(bf16x8*)(Al[buf] + i * 2048 + tid * 8) = pack8(ar[i][0], ar[i][1]);
  };
  auto stageA = [&](int buf, int k0) { // !AF32: async direct-to-LDS
#pragma unroll
    for (int i = 0; i < 4; ++i)
      gl2lds16(Ag + (size_t)(i * 32) * K + k0, Al[buf] + i * 2048 + w * 512);
  };
  auto stageB = [&](int buf, int k0) {
#pragma unroll
    for (int i = 0; i < BN / 32; ++i)  // FIXED: was NF*2 (=BN/16) -> OOB writes
      gl2lds16(Bg + (size_t)(i * 32) * K + k0, Bl[buf] + i * 2048 + w * 512);
  };
  auto compute = [&](int buf) {
    __builtin_amdgcn_s_setprio(1);
#pragma unroll
    for (int kk = 0; kk < 2; ++kk) {
      bf16x8 af[4], bfr[NF];
#pragma unroll
      for (int m = 0; m < 4; ++m) af[m]  = ldsfrag(Al[buf], wr * 64 + m * 16 + l15, kk * 4 + g);
#pragma unroll
      for (int n = 0; n < NF; ++n) bfr[n] = ldsfrag(Bl[buf], wc * (BN/2) + n * 16 + l15, kk * 4 + g);
#pragma unroll
      for (int m = 0; m < 4; ++m)
#pragma unroll
        for (int n = 0; n < NF; ++n)
          acc[m][n] = MFMA16(af[m], bfr[n], acc[m][n]);
    }
    __builtin_amdgcn_s_setprio(0);
  };

  // prologue
  if (AF32) { loadA(0); stageB(0, 0); writeA(0); }
  else      { stageA(0, 0); stageB(0, 0); }
  __syncthreads();
  int cur = 0;
  for (int k0 = 0; k0 < K; k0 += 64) {
    const bool more = (k0 + 64) < K;
    if (more) {
      if (AF32) loadA(k0 + 64);        // issue early: latency hides under MFMA
      else      stageA(cur ^ 1, k0 + 64);
      stageB(cur ^ 1, k0 + 64);
    }
    compute(cur);
    if (more && AF32) writeA(cur ^ 1); // cvt+write after compute (T14)
    __syncthreads();
    cur ^= 1;
  }

#pragma unroll
  for (int m = 0; m < 4; ++m) {
#pragma unroll
    for (int n = 0; n < NF; ++n) {
      const int row0 = rowBase + wr * 64 + m * 16 + g * 4;  // rows row0..row0+3
      const int col  = colBase + wc * (BN/2) + n * 16 + l15;
      if (mode == 1) {
        // rows = (b,l) with l consecutive over r; col = (h,e). Pack 4 l's.
        const int b = row0 >> 11, l = row0 & 2047;
        const int h = col >> 6,  e = col & 63;
        *(bf16x4*)((u16*)Cout + ((size_t)((((b << 4) + h) << 6) | e) << 11) + l) =
            pack4(acc[m][n][0], acc[m][n][1], acc[m][n][2], acc[m][n][3]);
      } else {
        const float bb = (mode == 4) ? bias[col] : 0.f;
#pragma unroll
        for (int r = 0; r < 4; ++r) {
          const int row = row0 + r;
          const float v = acc[m][n][r];
          if (mode == 0) {
            *(__bf16*)((u16*)Cout + (size_t)row * N + col) = (__bf16)(v * oscale);
          } else {
            *(__bf16*)((u16*)Cout + (size_t)row * N + col) = (__bf16)(v + bb);
          }
        }
      }
    }
  }
}

// log2(e)/8: folded into Q so attention softmax runs in exp2 domain.
#define QSCALE 0.18033688011112042f

// projections read the ORIGINAL fp32 inputs; bf16 conversion fused in staging
__global__ __launch_bounds__(256) void k_proj(
    const float* __restrict__ qf, const float* __restrict__ kf, const float* __restrict__ vf,
    const u16* __restrict__ wq, const u16* __restrict__ wk, const u16* __restrict__ wv,
    u16* __restrict__ Qp, u16* __restrict__ Kp, u16* __restrict__ Vt)
{
  const int z = blockIdx.z;
  const float* A = (z == 0) ? qf : (z == 1) ? kf : vf;
  const u16* B = (z == 0) ? wq : (z == 1) ? wk : wv;
  void* C = (z == 0) ? (void*)Qp : (z == 1) ? (void*)Kp : (void*)Vt;
  gemm_core<64, true>(A, B, 1024, 1024, (z == 2) ? 1 : 0, C, nullptr, (z == 0) ? QSCALE : 1.0f);
}

__global__ __launch_bounds__(256) void k_gemm_o(const u16* __restrict__ A,
                                                const u16* __restrict__ B,
                                                u16* __restrict__ C)
{ gemm_core<64, false>(A, B, 1024, 1024, 0, (void*)C, nullptr, 1.0f); }

__global__ __launch_bounds__(256) void k_gemm_fc(const u16* __restrict__ A,
                                                 const u16* __restrict__ B,
                                                 u16* __restrict__ C,
                                                 const float* __restrict__ bias)
{ gemm_core<64, false>(A, B, 1024, 1024, 4, (void*)C, bias, 1.0f); }

// ---------------------------------------------------------------------------
// Flash attention v6b, split-KV + register-fed PV (no P LDS), bf16 partials:
// grid (L/128, B*H, 2), 256 thr = 4 waves, each wave owns 32 q-rows (2 groups).
// S^T = mfma_16x16x32(K, Q): lane (l15,g) holds q=l15, k=f*16+g*4+r.
// P_f = pack4(exp2(s[f])) is EXACTLY the B-operand of mfma_16x16x16 for
// k-block f -> O^T[fe] += mfma_k16(V^T[fe][f], P_f).
// Static-max softmax; exact split combine O = (O0+O1)/(d0+d1).
// ---------------------------------------------------------------------------
__global__ __launch_bounds__(256, 4) void k_attn(const u16* __restrict__ Qp,
                                                 const u16* __restrict__ Kp,
                                                 const u16* __restrict__ Vt,
                                                 u16* __restrict__ Opart,
                                                 float* __restrict__ dpart)
{
  __shared__ u16 Klds[2][64 * 64];    // 16 KB
  __shared__ u16 Vlds[2][64 * 64];    // 16 KB

  const int tid = threadIdx.x, lane = tid & 63, w = tid >> 6;
  const int l15 = lane & 15, g = lane >> 4;
  const int bh = blockIdx.y, b = bh >> 4, h = bh & 15;
  const int q0 = blockIdx.x << 7;
  const int half = blockIdx.z;
  const int kvbase = half << 10;      // 0 or 1024

  // Q fragments (B-operand of QK): lane needs Q[q][e = kk*32 + g*8 ..+7]
  bf16x8 bq[2][2];
#pragma unroll
  for (int u = 0; u < 2; ++u) {
    const u16* Qr = Qp + (((size_t)((b << 11) + q0 + (w << 5) + (u << 4) + l15)) << 10)
                  + (h << 6) + (g << 3);
    bq[u][0] = *(const bf16x8*)(Qr);
    bq[u][1] = *(const bf16x8*)(Qr + 32);
  }

  const f32x4 zero4 = {0.f, 0.f, 0.f, 0.f};
  f32x4 o0[4], o1[4];
#pragma unroll
  for (int f = 0; f < 4; ++f) { o0[f] = zero4; o1[f] = zero4; }
  float ds0 = 0.f, ds1 = 0.f;

  const int srow = tid >> 3;
  const int swz  = ((tid & 7) ^ (srow & 7)) << 3;
  const u16* Kg = Kp + (((size_t)((b << 11) + kvbase + srow)) << 10) + (h << 6) + swz;
  const u16* Vg = Vt + (((size_t)((bh << 6) + srow)) << 11) + kvbase + swz;

  auto stage = [&](int buf, int j0) {
#pragma unroll
    for (int i = 0; i < 2; ++i) {
      gl2lds16(Kg + ((size_t)(j0 + i * 32) << 10), Klds[buf] + i * 2048 + w * 512);
      gl2lds16(Vg + ((size_t)(i * 32) << 11) + j0, Vlds[buf] + i * 2048 + w * 512);
    }
  };

  stage(0, 0);
  __syncthreads();
  int cur = 0;

  for (int j0 = 0; j0 < 1024; j0 += 64) {
    if (j0 + 64 < 1024) stage(cur ^ 1, j0 + 64);

    // S^T = K Q^T (log2 domain; scale pre-folded into Q). K frags shared by
    // both q-groups; per-f staging keeps register pressure low.
    f32x4 s0[4], s1[4];
    __builtin_amdgcn_s_setprio(1);
#pragma unroll
    for (int f = 0; f < 4; ++f) {
      const bf16x8 ka = ldsfrag(Klds[cur], f * 16 + l15, g);
      const bf16x8 kb = ldsfrag(Klds[cur], f * 16 + l15, 4 + g);
      s0[f] = MFMA16(ka, bq[0][0], zero4);
      s0[f] = MFMA16(kb, bq[0][1], s0[f]);
      s1[f] = MFMA16(ka, bq[1][0], zero4);
      s1[f] = MFMA16(kb, bq[1][1], s1[f]);
    }
    __builtin_amdgcn_s_setprio(0);

    // P = exp2(S) packed straight into PV B-operand fragments (in-register)
    bf16x4 p0[4], p1[4];
#pragma unroll
    for (int f = 0; f < 4; ++f) {
      const float a0 = __builtin_amdgcn_exp2f(s0[f][0]);
      const float a1 = __builtin_amdgcn_exp2f(s0[f][1]);
      const float a2 = __builtin_amdgcn_exp2f(s0[f][2]);
      const float a3 = __builtin_amdgcn_exp2f(s0[f][3]);
      ds0 += (a0 + a1) + (a2 + a3);
      p0[f] = pack4(a0, a1, a2, a3);
      const float c0 = __builtin_amdgcn_exp2f(s1[f][0]);
      const float c1 = __builtin_amdgcn_exp2f(s1[f][1]);
      const float c2 = __builtin_amdgcn_exp2f(s1[f][2]);
      const float c3 = __builtin_amdgcn_exp2f(s1[f][3]);
      ds1 += (c0 + c1) + (c2 + c3);
      p1[f] = pack4(c0, c1, c2, c3);
    }

    // O^T[fe] += V^T[fe][f] * P[f]  (A = b64 V frag, B = in-register P)
    __builtin_amdgcn_s_setprio(1);
#pragma unroll
    for (int fe = 0; fe < 4; ++fe) {
#pragma unroll
      for (int f = 0; f < 4; ++f) {
        const bf16x4 va = ldsfrag64(Vlds[cur], fe * 16 + l15, 2 * f + (g >> 1), g & 1);
        o0[fe] = mfma_k16(va, p0[f], o0[fe]);
        o1[fe] = mfma_k16(va, p1[f], o1[fe]);
      }
    }
    __builtin_amdgcn_s_setprio(0);
    __syncthreads();
    cur ^= 1;
  }

  // partial denominators: sum the 4 disjoint k-subsets held by the 4 g-groups
  ds0 += __shfl_xor(ds0, 16, 64);
  ds0 += __shfl_xor(ds0, 32, 64);
  ds1 += __shfl_xor(ds1, 16, 64);
  ds1 += __shfl_xor(ds1, 32, 64);

  const int brow0 = (b << 11) + q0 + (w << 5) + l15;   // row in [0, B*L)
  const int brow1 = brow0 + 16;
  u16* Op = Opart + ((size_t)half << 22);              // half * 4096*1024 elems
#pragma unroll
  for (int f = 0; f < 4; ++f) {
    *(bf16x4*)(Op + (((size_t)brow0) << 10) + (h << 6) + f * 16 + (g << 2)) =
        pack4(o0[f][0], o0[f][1], o0[f][2], o0[f][3]);
    *(bf16x4*)(Op + (((size_t)brow1) << 10) + (h << 6) + f * 16 + (g << 2)) =
        pack4(o1[f][0], o1[f][1], o1[f][2], o1[f][3]);
  }
  if (g == 0) {
    dpart[(half << 16) + (brow0 << 4) + h] = ds0;
    dpart[(half << 16) + (brow1 << 4) + h] = ds1;
  }
}

// ---------------------------------------------------------------------------
// split-KV combine: ctx = (O0 + O1) / (d0 + d1), bf16 in/out. 1 block per row.
// ---------------------------------------------------------------------------
__global__ __launch_bounds__(256) void k_combine(const u16* __restrict__ Opart,
                                                 const float* __restrict__ dpart,
                                                 u16* __restrict__ ctx)
{
  const int row = blockIdx.x, tid = threadIdx.x;
  const int h = tid >> 4;
  const float d = dpart[(row << 4) + h] + dpart[(1 << 16) + (row << 4) + h];
  const float inv = 1.0f / d;
  const bf16x4 p0 = ((const bf16x4*)(Opart + ((size_t)row << 10)))[tid];
  const bf16x4 p1 = ((const bf16x4*)(Opart + (1u << 22) + ((size_t)row << 10)))[tid];
  ((bf16x4*)(ctx + ((size_t)row << 10)))[tid] =
      pack4(((float)p0[0] + (float)p1[0]) * inv, ((float)p0[1] + (float)p1[1]) * inv,
            ((float)p0[2] + (float)p1[2]) * inv, ((float)p0[3] + (float)p1[3]) * inv);
}

// ---------------------------------------------------------------------------
// fused add + LayerNorm over D=1024 (one row per block, 256 thr x 4 elems)
// ln1: a bf16 + res f32 -> bf16 out.   ln2: a bf16 + res bf16 -> f32 out.
// ---------------------------------------------------------------------------
__device__ __forceinline__ void ln_stats(float4 t, int tid, float& mean, float& inv){
  float s = t.x + t.y + t.z + t.w;
  float q = t.x * t.x + t.y * t.y + t.z * t.z + t.w * t.w;
#pragma unroll
  for (int d = 1; d < 64; d <<= 1) {
    s += __shfl_xor(s, d, 64);
    q += __shfl_xor(q, d, 64);
  }
  __shared__ float ps[4], pq[4];
  const int w = tid >> 6;
  if ((tid & 63) == 0) { ps[w] = s; pq[w] = q; }
  __syncthreads();
  s = ps[0] + ps[1] + ps[2] + ps[3];
  q = pq[0] + pq[1] + pq[2] + pq[3];
  mean = s * (1.0f / 1024.0f);
  const float var = q * (1.0f / 1024.0f) - mean * mean;
  inv = rsqrtf(var + 1e-5f);
}

__global__ __launch_bounds__(256) void k_ln1(const u16* __restrict__ a,
                                             const float* __restrict__ res,
                                             u16* __restrict__ xb)
{
  const int row = blockIdx.x, tid = threadIdx.x;
  const size_t base = (size_t)row << 10;
  const bf16x4 av = ((const bf16x4*)(a + base))[tid];
  const float4 rr = ((const float4*)(res + base))[tid];
  float4 t;
  t.x = (float)av[0] + rr.x; t.y = (float)av[1] + rr.y;
  t.z = (float)av[2] + rr.z; t.w = (float)av[3] + rr.w;
  float mean, inv;
  ln_stats(t, tid, mean, inv);
  ((bf16x4*)(xb + base))[tid] = pack4((t.x - mean) * inv, (t.y - mean) * inv,
                                      (t.z - mean) * inv, (t.w - mean) * inv);
}

__global__ __launch_bounds__(256) void k_ln2(const u16* __restrict__ a,
                                             const u16* __restrict__ res,
                                             float* __restrict__ out)
{
  const int row = blockIdx.x, tid = threadIdx.x;
  const size_t base = (size_t)row << 10;
  const bf16x4 av = ((const bf16x4*)(a + base))[tid];
  const bf16x4 rv = ((const bf16x4*)(res + base))[tid];
  float4 t;
  t.x = (float)av[0] + (float)rv[0]; t.y = (float)av[1] + (float)rv[1];
  t.z = (float)av[2] + (float)rv[2]; t.w = (float)av[3] + (float)rv[3];
  float mean, inv;
  ln_stats(t, tid, mean, inv);
  float4 o;
  o.x = (t.x - mean) * inv; o.y = (t.y - mean) * inv;
  o.z = (t.z - mean) * inv; o.w = (t.w - mean) * inv;
  ((float4*)(out + base))[tid] = o;
}

// fp32 -> bf16 converter for the 5 weight matrices
__global__ __launch_bounds__(256) void k_cvt5(const float* __restrict__ a0,
                                              const float* __restrict__ a1,
                                              const float* __restrict__ a2,
                                              const float* __restrict__ a3,
                                              const float* __restrict__ a4,
                                              u16* __restrict__ o0, u16* __restrict__ o1,
                                              u16* __restrict__ o2, u16* __restrict__ o3,
                                              u16* __restrict__ o4)
{
  const int z = blockIdx.y;
  const float* src = (z == 0) ? a0 : (z == 1) ? a1 : (z == 2) ? a2 : (z == 3) ? a3 : a4;
  u16* dst = (z == 0) ? o0 : (z == 1) ? o1 : (z == 2) ? o2 : (z == 3) ? o3 : o4;
  const int i = blockIdx.x * 256 + threadIdx.x;
  const float4 t = ((const float4*)src)[i];
  ((bf16x4*)dst)[i] = pack4(t.x, t.y, t.z, t.w);
}

extern "C" void kernel_launch(void* const* d_in, const int* in_sizes, int n_in,
                              void* d_out, int out_size, void* d_ws, size_t ws_size,
                              hipStream_t stream)
{
  (void)in_sizes; (void)n_in; (void)out_size; (void)ws_size;
  const float* query = (const float*)d_in[0];
  const float* key   = (const float*)d_in[1];
  const float* value = (const float*)d_in[2];
  const float* W_Q   = (const float*)d_in[3];
  const float* W_K   = (const float*)d_in[4];
  const float* W_V   = (const float*)d_in[5];
  const float* W_O   = (const float*)d_in[6];
  const float* fc_w  = (const float*)d_in[7];
  const float* fc_b  = (const float*)d_in[8];
  float* out = (float*)d_out;
  char* ws = (char*)d_ws;

  // workspace layout (bytes)
  u16*   xb    = (u16*)(ws + 0);          //  8.39 MB
  u16*   yb    = (u16*)(ws + 8388608);    //  8.39 MB
  u16*   wq    = (u16*)(ws + 25165824);
  u16*   wk    = (u16*)(ws + 27262976);
  u16*   wv    = (u16*)(ws + 29360128);
  u16*   wo    = (u16*)(ws + 31457280);
  u16*   fw    = (u16*)(ws + 33554432);
  u16*   Qp    = (u16*)(ws + 35651584);
  u16*   Kp    = (u16*)(ws + 44040192);
  u16*   Vt    = (u16*)(ws + 52428800);
  u16*   ctx   = (u16*)(ws + 60817408);
  u16*   Opart = (u16*)(ws + 69206016);   // 16.78 MB (2 x 8.39 bf16)
  float* dpart = (float*)(ws + 85983232); //  0.52 MB ; total ~86.5 MB
  u16*   attnb = (u16*)(ws + 69206016);   // aliases Opart (temporally disjoint)

  k_cvt5<<<dim3(1024, 5), 256, 0, stream>>>(W_Q, W_K, W_V, W_O, fc_w, wq, wk, wv, wo, fw);
  k_proj<<<dim3(16, 32, 3), 256, 0, stream>>>(query, key, value, wq, wk, wv, Qp, Kp, Vt);
  k_attn<<<dim3(16, 32, 2), 256, 0, stream>>>(Qp, Kp, Vt, Opart, dpart);
  k_combine<<<dim3(4096), 256, 0, stream>>>(Opart, dpart, ctx);
  k_gemm_o<<<dim3(16, 32), 256, 0, stream>>>(ctx, wo, attnb);
  k_ln1<<<dim3(4096), 256, 0, stream>>>(attnb, query, xb);
  k_gemm_fc<<<dim3(16, 32), 256, 0, stream>>>(xb, fw, yb, fc_b);
  k_ln2<<<dim3(4096), 256, 0, stream>>>(yb, xb, out);
}

// Round 12
// 155.441 us; speedup vs baseline: 1.1367x; 1.1367x over previous
//
#include <hip/hip_runtime.h>
#include <stdint.h>

typedef unsigned short u16;
typedef __bf16 bf16x8 __attribute__((ext_vector_type(8)));
typedef __bf16 bf16x4 __attribute__((ext_vector_type(4)));
typedef short s16x4 __attribute__((ext_vector_type(4)));
typedef float f32x4 __attribute__((ext_vector_type(4)));

#define MFMA16(a,b,c) __builtin_amdgcn_mfma_f32_16x16x32_bf16((a),(b),(c),0,0,0)

// K=16 MFMA: D = A(16x16) * B(16x16) + C. B-operand layout (col=l15, k=g*4+j)
// matches the 16x16 C/D layout (col=l15, row=g*4+r) -> S^T regs feed PV directly.
__device__ __forceinline__ f32x4 mfma_k16(bf16x4 a, bf16x4 b, f32x4 c){
#if __has_builtin(__builtin_amdgcn_mfma_f32_16x16x16_bf16)
  return __builtin_amdgcn_mfma_f32_16x16x16_bf16(a, b, c, 0, 0, 0);
#elif __has_builtin(__builtin_amdgcn_mfma_f32_16x16x16bf16_1k)
  s16x4 ai, bi;
  __builtin_memcpy(&ai, &a, 8);
  __builtin_memcpy(&bi, &b, 8);
  return __builtin_amdgcn_mfma_f32_16x16x16bf16_1k(ai, bi, c, 0, 0, 0);
#else
  asm("v_mfma_f32_16x16x16_bf16 %0, %1, %2, %0" : "+v"(c) : "v"(a), "v"(b));
  return c;
#endif
}

__device__ __forceinline__ bf16x4 pack4(float a, float b, float c, float d){
  bf16x4 r; r[0]=(__bf16)a; r[1]=(__bf16)b; r[2]=(__bf16)c; r[3]=(__bf16)d; return r;
}
__device__ __forceinline__ bf16x8 pack8(float4 a, float4 b){
  bf16x8 r;
  r[0]=(__bf16)a.x; r[1]=(__bf16)a.y; r[2]=(__bf16)a.z; r[3]=(__bf16)a.w;
  r[4]=(__bf16)b.x; r[5]=(__bf16)b.y; r[6]=(__bf16)b.z; r[7]=(__bf16)b.w;
  return r;
}

__device__ __forceinline__ void gl2lds16(const void* g, void* l){
  __builtin_amdgcn_global_load_lds(
      (const __attribute__((address_space(1))) unsigned int*)g,
      (__attribute__((address_space(3))) unsigned int*)l, 16, 0, 0);
}

// Read one bf16x8 MFMA fragment from a [rows][64-elem] XOR-swizzled LDS tile.
// Physical granule slot = logical_granule ^ (row & 7)  (16B granules, 8/row).
__device__ __forceinline__ bf16x8 ldsfrag(const u16* base, int row, int gr){
  return *(const bf16x8*)(base + row * 64 + ((gr ^ (row & 7)) << 3));
}
// b64 variant: granule gr, half h (0/1 -> 4-elem offset).
__device__ __forceinline__ bf16x4 ldsfrag64(const u16* base, int row, int gr, int h){
  return *(const bf16x4*)(base + row * 64 + ((gr ^ (row & 7)) << 3) + (h << 2));
}

// XCD-locality remap (T1): hw round-robins consecutive flat ids across 8 XCDs.
// Remap so each XCD walks tile-x fastest within its OWN contiguous y-panels ->
// blocks sharing an A-panel (same y) co-locate on one XCD and hit its L2.
// Requires nY % 8 == 0. Bijective.
__device__ __forceinline__ void xcd_remap(int& tx, int& ty){
  const int nX = (int)gridDim.x, nY = (int)gridDim.y;
  const int flat = (int)blockIdx.x + nX * (int)blockIdx.y;
  const int xcd = flat & 7, j = flat >> 3;
  tx = j % nX;
  ty = xcd * (nY >> 3) + j / nX;
}

// ---------------------------------------------------------------------------
// GEMM core: C[M,N] = A[M,K] @ Bt[N,K]^T, fp32 accumulate, double-buffered LDS.
// Block = 256 thr (4 waves, 2x2), tile 128 x BN, BK=64. XCD-swizzled tiles.
// AF32: A is fp32 in global; reg-staged (load f32 early -> cvt -> ds_write
// after compute, T14 pattern). Fuses the bf16 conversion into the GEMM.
// !AF32: A is bf16; async global_load_lds staging.
// mode 0: bf16 C [row*N+col], scaled by oscale
// mode 1: bf16 C transposed-V layout:  [((b*16+h)*64+e)*2048 + l], packed x4
// mode 4: bf16 C + bias[col]
// ---------------------------------------------------------------------------
template<int BN, bool AF32>
__device__ __forceinline__ void gemm_core(const void* __restrict__ Araw,
                                          const u16* __restrict__ Bt,
                                          int N, int K, int mode,
                                          void* __restrict__ Cout,
                                          const float* __restrict__ bias,
                                          float oscale)
{
  constexpr int NF = BN / 32;          // B-frags per wave (wave covers BN/2 cols)
  __shared__ u16 Al[2][128 * 64];
  __shared__ u16 Bl[2][BN * 64];
  const int tid  = threadIdx.x;
  const int lane = tid & 63;
  const int w    = tid >> 6;
  const int wr   = w >> 1, wc = w & 1;
  const int l15  = lane & 15, g = lane >> 4;
  int tx, ty;
  xcd_remap(tx, ty);
  const int rowBase = ty << 7;
  const int colBase = tx * BN;

  // staging: thread t handles row (i*32 + t/8), granule t%8, pre-swizzled col
  const int srow = tid >> 3;                          // 0..31
  const int swz  = ((tid & 7) ^ (srow & 7)) << 3;     // element offset in row
  const u16*   Ag  = AF32 ? nullptr : (const u16*)Araw + (size_t)(rowBase + srow) * K + swz;
  const float* Agf = AF32 ? (const float*)Araw + (size_t)(rowBase + srow) * K + swz : nullptr;
  const u16*   Bg  = Bt + (size_t)(colBase + srow) * K + swz;

  f32x4 acc[4][NF];
#pragma unroll
  for (int m = 0; m < 4; ++m)
#pragma unroll
    for (int n = 0; n < NF; ++n) acc[m][n] = f32x4{0.f, 0.f, 0.f, 0.f};

  float4 ar[4][2];                     // in-flight f32 A granules (AF32 path)
  auto loadA = [&](int k0) {
    if (AF32) {
#pragma unroll
      for (int i = 0; i < 4; ++i) {
        const float* p = Agf + (size_t)(i * 32) * K + k0;
        ar[i][0] = *(const float4*)p;
        ar[i][1] = *(const float4*)(p + 4);
      }
    }
  };
  auto writeA = [&](int buf) {         // AF32: cvt + ds_write (after compute)
#pragma unroll
    for (int i = 0; i < 4; ++i)
      *(bf16x8*)(Al[buf] + i * 2048 + tid * 8) = pack8(ar[i][0], ar[i][1]);
  };
  auto stageA = [&](int buf, int k0) { // !AF32: async direct-to-LDS
#pragma unroll
    for (int i = 0; i < 4; ++i)
      gl2lds16(Ag + (size_t)(i * 32) * K + k0, Al[buf] + i * 2048 + w * 512);
  };
  auto stageB = [&](int buf, int k0) {
#pragma unroll
    for (int i = 0; i < BN / 32; ++i)
      gl2lds16(Bg + (size_t)(i * 32) * K + k0, Bl[buf] + i * 2048 + w * 512);
  };
  auto compute = [&](int buf) {
    __builtin_amdgcn_s_setprio(1);
#pragma unroll
    for (int kk = 0; kk < 2; ++kk) {
      bf16x8 af[4], bfr[NF];
#pragma unroll
      for (int m = 0; m < 4; ++m) af[m]  = ldsfrag(Al[buf], wr * 64 + m * 16 + l15, kk * 4 + g);
#pragma unroll
      for (int n = 0; n < NF; ++n) bfr[n] = ldsfrag(Bl[buf], wc * (BN/2) + n * 16 + l15, kk * 4 + g);
#pragma unroll
      for (int m = 0; m < 4; ++m)
#pragma unroll
        for (int n = 0; n < NF; ++n)
          acc[m][n] = MFMA16(af[m], bfr[n], acc[m][n]);
    }
    __builtin_amdgcn_s_setprio(0);
  };

  // prologue
  if (AF32) { loadA(0); stageB(0, 0); writeA(0); }
  else      { stageA(0, 0); stageB(0, 0); }
  __syncthreads();
  int cur = 0;
  for (int k0 = 0; k0 < K; k0 += 64) {
    const bool more = (k0 + 64) < K;
    if (more) {
      if (AF32) loadA(k0 + 64);        // issue early: latency hides under MFMA
      else      stageA(cur ^ 1, k0 + 64);
      stageB(cur ^ 1, k0 + 64);
    }
    compute(cur);
    if (more && AF32) writeA(cur ^ 1); // cvt+write after compute (T14)
    __syncthreads();
    cur ^= 1;
  }

#pragma unroll
  for (int m = 0; m < 4; ++m) {
#pragma unroll
    for (int n = 0; n < NF; ++n) {
      const int row0 = rowBase + wr * 64 + m * 16 + g * 4;  // rows row0..row0+3
      const int col  = colBase + wc * (BN/2) + n * 16 + l15;
      if (mode == 1) {
        // rows = (b,l) with l consecutive over r; col = (h,e). Pack 4 l's.
        const int b = row0 >> 11, l = row0 & 2047;
        const int h = col >> 6,  e = col & 63;
        *(bf16x4*)((u16*)Cout + ((size_t)((((b << 4) + h) << 6) | e) << 11) + l) =
            pack4(acc[m][n][0], acc[m][n][1], acc[m][n][2], acc[m][n][3]);
      } else {
        const float bb = (mode == 4) ? bias[col] : 0.f;
#pragma unroll
        for (int r = 0; r < 4; ++r) {
          const int row = row0 + r;
          const float v = acc[m][n][r];
          if (mode == 0) {
            *(__bf16*)((u16*)Cout + (size_t)row * N + col) = (__bf16)(v * oscale);
          } else {
            *(__bf16*)((u16*)Cout + (size_t)row * N + col) = (__bf16)(v + bb);
          }
        }
      }
    }
  }
}

// log2(e)/8: folded into Q so attention softmax runs in exp2 domain.
#define QSCALE 0.18033688011112042f

// projections read the ORIGINAL fp32 inputs; bf16 conversion fused in staging
__global__ __launch_bounds__(256) void k_proj(
    const float* __restrict__ qf, const float* __restrict__ kf, const float* __restrict__ vf,
    const u16* __restrict__ wq, const u16* __restrict__ wk, const u16* __restrict__ wv,
    u16* __restrict__ Qp, u16* __restrict__ Kp, u16* __restrict__ Vt)
{
  const int z = blockIdx.z;
  const float* A = (z == 0) ? qf : (z == 1) ? kf : vf;
  const u16* B = (z == 0) ? wq : (z == 1) ? wk : wv;
  void* C = (z == 0) ? (void*)Qp : (z == 1) ? (void*)Kp : (void*)Vt;
  gemm_core<64, true>(A, B, 1024, 1024, (z == 2) ? 1 : 0, C, nullptr, (z == 0) ? QSCALE : 1.0f);
}

__global__ __launch_bounds__(256) void k_gemm_o(const u16* __restrict__ A,
                                                const u16* __restrict__ B,
                                                u16* __restrict__ C)
{ gemm_core<64, false>(A, B, 1024, 1024, 0, (void*)C, nullptr, 1.0f); }

__global__ __launch_bounds__(256) void k_gemm_fc(const u16* __restrict__ A,
                                                 const u16* __restrict__ B,
                                                 u16* __restrict__ C,
                                                 const float* __restrict__ bias)
{ gemm_core<64, false>(A, B, 1024, 1024, 4, (void*)C, bias, 1.0f); }

// ---------------------------------------------------------------------------
// Flash attention v6c, split-KV + register-fed PV (no P LDS), bf16 partials,
// XCD-swizzled tiles (blocks sharing a head's K/V co-locate on one XCD):
// grid (L/128, B*H, 2), 256 thr = 4 waves, each wave owns 32 q-rows (2 groups).
// S^T = mfma_16x16x32(K, Q): lane (l15,g) holds q=l15, k=f*16+g*4+r.
// P_f = pack4(exp2(s[f])) is EXACTLY the B-operand of mfma_16x16x16 for
// k-block f -> O^T[fe] += mfma_k16(V^T[fe][f], P_f).
// Static-max softmax; exact split combine O = (O0+O1)/(d0+d1).
// ---------------------------------------------------------------------------
__global__ __launch_bounds__(256, 4) void k_attn(const u16* __restrict__ Qp,
                                                 const u16* __restrict__ Kp,
                                                 const u16* __restrict__ Vt,
                                                 u16* __restrict__ Opart,
                                                 float* __restrict__ dpart)
{
  __shared__ u16 Klds[2][64 * 64];    // 16 KB
  __shared__ u16 Vlds[2][64 * 64];    // 16 KB

  const int tid = threadIdx.x, lane = tid & 63, w = tid >> 6;
  const int l15 = lane & 15, g = lane >> 4;
  int tx, ty;
  xcd_remap(tx, ty);                  // tx = q-tile, ty = bh (panels share K/V)
  const int bh = ty, b = bh >> 4, h = bh & 15;
  const int q0 = tx << 7;
  const int half = blockIdx.z;
  const int kvbase = half << 10;      // 0 or 1024

  // Q fragments (B-operand of QK): lane needs Q[q][e = kk*32 + g*8 ..+7]
  bf16x8 bq[2][2];
#pragma unroll
  for (int u = 0; u < 2; ++u) {
    const u16* Qr = Qp + (((size_t)((b << 11) + q0 + (w << 5) + (u << 4) + l15)) << 10)
                  + (h << 6) + (g << 3);
    bq[u][0] = *(const bf16x8*)(Qr);
    bq[u][1] = *(const bf16x8*)(Qr + 32);
  }

  const f32x4 zero4 = {0.f, 0.f, 0.f, 0.f};
  f32x4 o0[4], o1[4];
#pragma unroll
  for (int f = 0; f < 4; ++f) { o0[f] = zero4; o1[f] = zero4; }
  float ds0 = 0.f, ds1 = 0.f;

  const int srow = tid >> 3;
  const int swz  = ((tid & 7) ^ (srow & 7)) << 3;
  const u16* Kg = Kp + (((size_t)((b << 11) + kvbase + srow)) << 10) + (h << 6) + swz;
  const u16* Vg = Vt + (((size_t)((bh << 6) + srow)) << 11) + kvbase + swz;

  auto stage = [&](int buf, int j0) {
#pragma unroll
    for (int i = 0; i < 2; ++i) {
      gl2lds16(Kg + ((size_t)(j0 + i * 32) << 10), Klds[buf] + i * 2048 + w * 512);
      gl2lds16(Vg + ((size_t)(i * 32) << 11) + j0, Vlds[buf] + i * 2048 + w * 512);
    }
  };

  stage(0, 0);
  __syncthreads();
  int cur = 0;

  for (int j0 = 0; j0 < 1024; j0 += 64) {
    if (j0 + 64 < 1024) stage(cur ^ 1, j0 + 64);

    // S^T = K Q^T (log2 domain; scale pre-folded into Q). K frags shared by
    // both q-groups; per-f staging keeps register pressure low.
    f32x4 s0[4], s1[4];
    __builtin_amdgcn_s_setprio(1);
#pragma unroll
    for (int f = 0; f < 4; ++f) {
      const bf16x8 ka = ldsfrag(Klds[cur], f * 16 + l15, g);
      const bf16x8 kb = ldsfrag(Klds[cur], f * 16 + l15, 4 + g);
      s0[f] = MFMA16(ka, bq[0][0], zero4);
      s0[f] = MFMA16(kb, bq[0][1], s0[f]);
      s1[f] = MFMA16(ka, bq[1][0], zero4);
      s1[f] = MFMA16(kb, bq[1][1], s1[f]);
    }
    __builtin_amdgcn_s_setprio(0);

    // P = exp2(S) packed straight into PV B-operand fragments (in-register)
    bf16x4 p0[4], p1[4];
#pragma unroll
    for (int f = 0; f < 4; ++f) {
      const float a0 = __builtin_amdgcn_exp2f(s0[f][0]);
      const float a1 = __builtin_amdgcn_exp2f(s0[f][1]);
      const float a2 = __builtin_amdgcn_exp2f(s0[f][2]);
      const float a3 = __builtin_amdgcn_exp2f(s0[f][3]);
      ds0 += (a0 + a1) + (a2 + a3);
      p0[f] = pack4(a0, a1, a2, a3);
      const float c0 = __builtin_amdgcn_exp2f(s1[f][0]);
      const float c1 = __builtin_amdgcn_exp2f(s1[f][1]);
      const float c2 = __builtin_amdgcn_exp2f(s1[f][2]);
      const float c3 = __builtin_amdgcn_exp2f(s1[f][3]);
      ds1 += (c0 + c1) + (c2 + c3);
      p1[f] = pack4(c0, c1, c2, c3);
    }

    // O^T[fe] += V^T[fe][f] * P[f]  (A = b64 V frag, B = in-register P)
    __builtin_amdgcn_s_setprio(1);
#pragma unroll
    for (int fe = 0; fe < 4; ++fe) {
#pragma unroll
      for (int f = 0; f < 4; ++f) {
        const bf16x4 va = ldsfrag64(Vlds[cur], fe * 16 + l15, 2 * f + (g >> 1), g & 1);
        o0[fe] = mfma_k16(va, p0[f], o0[fe]);
        o1[fe] = mfma_k16(va, p1[f], o1[fe]);
      }
    }
    __builtin_amdgcn_s_setprio(0);
    __syncthreads();
    cur ^= 1;
  }

  // partial denominators: sum the 4 disjoint k-subsets held by the 4 g-groups
  ds0 += __shfl_xor(ds0, 16, 64);
  ds0 += __shfl_xor(ds0, 32, 64);
  ds1 += __shfl_xor(ds1, 16, 64);
  ds1 += __shfl_xor(ds1, 32, 64);

  const int brow0 = (b << 11) + q0 + (w << 5) + l15;   // row in [0, B*L)
  const int brow1 = brow0 + 16;
  u16* Op = Opart + ((size_t)half << 22);              // half * 4096*1024 elems
#pragma unroll
  for (int f = 0; f < 4; ++f) {
    *(bf16x4*)(Op + (((size_t)brow0) << 10) + (h << 6) + f * 16 + (g << 2)) =
        pack4(o0[f][0], o0[f][1], o0[f][2], o0[f][3]);
    *(bf16x4*)(Op + (((size_t)brow1) << 10) + (h << 6) + f * 16 + (g << 2)) =
        pack4(o1[f][0], o1[f][1], o1[f][2], o1[f][3]);
  }
  if (g == 0) {
    dpart[(half << 16) + (brow0 << 4) + h] = ds0;
    dpart[(half << 16) + (brow1 << 4) + h] = ds1;
  }
}

// ---------------------------------------------------------------------------
// split-KV combine: ctx = (O0 + O1) / (d0 + d1), bf16 in/out. 1 block per row.
// ---------------------------------------------------------------------------
__global__ __launch_bounds__(256) void k_combine(const u16* __restrict__ Opart,
                                                 const float* __restrict__ dpart,
                                                 u16* __restrict__ ctx)
{
  const int row = blockIdx.x, tid = threadIdx.x;
  const int h = tid >> 4;
  const float d = dpart[(row << 4) + h] + dpart[(1 << 16) + (row << 4) + h];
  const float inv = 1.0f / d;
  const bf16x4 p0 = ((const bf16x4*)(Opart + ((size_t)row << 10)))[tid];
  const bf16x4 p1 = ((const bf16x4*)(Opart + (1u << 22) + ((size_t)row << 10)))[tid];
  ((bf16x4*)(ctx + ((size_t)row << 10)))[tid] =
      pack4(((float)p0[0] + (float)p1[0]) * inv, ((float)p0[1] + (float)p1[1]) * inv,
            ((float)p0[2] + (float)p1[2]) * inv, ((float)p0[3] + (float)p1[3]) * inv);
}

// ---------------------------------------------------------------------------
// fused add + LayerNorm over D=1024 (one row per block, 256 thr x 4 elems)
// ln1: a bf16 + res f32 -> bf16 out.   ln2: a bf16 + res bf16 -> f32 out.
// ---------------------------------------------------------------------------
__device__ __forceinline__ void ln_stats(float4 t, int tid, float& mean, float& inv){
  float s = t.x + t.y + t.z + t.w;
  float q = t.x * t.x + t.y * t.y + t.z * t.z + t.w * t.w;
#pragma unroll
  for (int d = 1; d < 64; d <<= 1) {
    s += __shfl_xor(s, d, 64);
    q += __shfl_xor(q, d, 64);
  }
  __shared__ float ps[4], pq[4];
  const int w = tid >> 6;
  if ((tid & 63) == 0) { ps[w] = s; pq[w] = q; }
  __syncthreads();
  s = ps[0] + ps[1] + ps[2] + ps[3];
  q = pq[0] + pq[1] + pq[2] + pq[3];
  mean = s * (1.0f / 1024.0f);
  const float var = q * (1.0f / 1024.0f) - mean * mean;
  inv = rsqrtf(var + 1e-5f);
}

__global__ __launch_bounds__(256) void k_ln1(const u16* __restrict__ a,
                                             const float* __restrict__ res,
                                             u16* __restrict__ xb)
{
  const int row = blockIdx.x, tid = threadIdx.x;
  const size_t base = (size_t)row << 10;
  const bf16x4 av = ((const bf16x4*)(a + base))[tid];
  const float4 rr = ((const float4*)(res + base))[tid];
  float4 t;
  t.x = (float)av[0] + rr.x; t.y = (float)av[1] + rr.y;
  t.z = (float)av[2] + rr.z; t.w = (float)av[3] + rr.w;
  float mean, inv;
  ln_stats(t, tid, mean, inv);
  ((bf16x4*)(xb + base))[tid] = pack4((t.x - mean) * inv, (t.y - mean) * inv,
                                      (t.z - mean) * inv, (t.w - mean) * inv);
}

__global__ __launch_bounds__(256) void k_ln2(const u16* __restrict__ a,
                                             const u16* __restrict__ res,
                                             float* __restrict__ out)
{
  const int row = blockIdx.x, tid = threadIdx.x;
  const size_t base = (size_t)row << 10;
  const bf16x4 av = ((const bf16x4*)(a + base))[tid];
  const bf16x4 rv = ((const bf16x4*)(res + base))[tid];
  float4 t;
  t.x = (float)av[0] + (float)rv[0]; t.y = (float)av[1] + (float)rv[1];
  t.z = (float)av[2] + (float)rv[2]; t.w = (float)av[3] + (float)rv[3];
  float mean, inv;
  ln_stats(t, tid, mean, inv);
  float4 o;
  o.x = (t.x - mean) * inv; o.y = (t.y - mean) * inv;
  o.z = (t.z - mean) * inv; o.w = (t.w - mean) * inv;
  ((float4*)(out + base))[tid] = o;
}

// fp32 -> bf16 converter for the 5 weight matrices
__global__ __launch_bounds__(256) void k_cvt5(const float* __restrict__ a0,
                                              const float* __restrict__ a1,
                                              const float* __restrict__ a2,
                                              const float* __restrict__ a3,
                                              const float* __restrict__ a4,
                                              u16* __restrict__ o0, u16* __restrict__ o1,
                                              u16* __restrict__ o2, u16* __restrict__ o3,
                                              u16* __restrict__ o4)
{
  const int z = blockIdx.y;
  const float* src = (z == 0) ? a0 : (z == 1) ? a1 : (z == 2) ? a2 : (z == 3) ? a3 : a4;
  u16* dst = (z == 0) ? o0 : (z == 1) ? o1 : (z == 2) ? o2 : (z == 3) ? o3 : o4;
  const int i = blockIdx.x * 256 + threadIdx.x;
  const float4 t = ((const float4*)src)[i];
  ((bf16x4*)dst)[i] = pack4(t.x, t.y, t.z, t.w);
}

extern "C" void kernel_launch(void* const* d_in, const int* in_sizes, int n_in,
                              void* d_out, int out_size, void* d_ws, size_t ws_size,
                              hipStream_t stream)
{
  (void)in_sizes; (void)n_in; (void)out_size; (void)ws_size;
  const float* query = (const float*)d_in[0];
  const float* key   = (const float*)d_in[1];
  const float* value = (const float*)d_in[2];
  const float* W_Q   = (const float*)d_in[3];
  const float* W_K   = (const float*)d_in[4];
  const float* W_V   = (const float*)d_in[5];
  const float* W_O   = (const float*)d_in[6];
  const float* fc_w  = (const float*)d_in[7];
  const float* fc_b  = (const float*)d_in[8];
  float* out = (float*)d_out;
  char* ws = (char*)d_ws;

  // workspace layout (bytes)
  u16*   xb    = (u16*)(ws + 0);          //  8.39 MB
  u16*   yb    = (u16*)(ws + 8388608);    //  8.39 MB
  u16*   wq    = (u16*)(ws + 25165824);
  u16*   wk    = (u16*)(ws + 27262976);
  u16*   wv    = (u16*)(ws + 29360128);
  u16*   wo    = (u16*)(ws + 31457280);
  u16*   fw    = (u16*)(ws + 33554432);
  u16*   Qp    = (u16*)(ws + 35651584);
  u16*   Kp    = (u16*)(ws + 44040192);
  u16*   Vt    = (u16*)(ws + 52428800);
  u16*   ctx   = (u16*)(ws + 60817408);
  u16*   Opart = (u16*)(ws + 69206016);   // 16.78 MB (2 x 8.39 bf16)
  float* dpart = (float*)(ws + 85983232); //  0.52 MB ; total ~86.5 MB
  u16*   attnb = (u16*)(ws + 69206016);   // aliases Opart (temporally disjoint)

  k_cvt5<<<dim3(1024, 5), 256, 0, stream>>>(W_Q, W_K, W_V, W_O, fc_w, wq, wk, wv, wo, fw);
  k_proj<<<dim3(16, 32, 3), 256, 0, stream>>>(query, key, value, wq, wk, wv, Qp, Kp, Vt);
  k_attn<<<dim3(16, 32, 2), 256, 0, stream>>>(Qp, Kp, Vt, Opart, dpart);
  k_combine<<<dim3(4096), 256, 0, stream>>>(Opart, dpart, ctx);
  k_gemm_o<<<dim3(16, 32), 256, 0, stream>>>(ctx, wo, attnb);
  k_ln1<<<dim3(4096), 256, 0, stream>>>(attnb, query, xb);
  k_gemm_fc<<<dim3(16, 32), 256, 0, stream>>>(xb, fw, yb, fc_b);
  k_ln2<<<dim3(4096), 256, 0, stream>>>(yb, xb, out);
}

// Round 13
// 150.442 us; speedup vs baseline: 1.1744x; 1.0332x over previous
//
#include <hip/hip_runtime.h>
#include <stdint.h>

typedef unsigned short u16;
typedef __bf16 bf16x8 __attribute__((ext_vector_type(8)));
typedef __bf16 bf16x4 __attribute__((ext_vector_type(4)));
typedef short s16x4 __attribute__((ext_vector_type(4)));
typedef float f32x4 __attribute__((ext_vector_type(4)));

#define MFMA16(a,b,c) __builtin_amdgcn_mfma_f32_16x16x32_bf16((a),(b),(c),0,0,0)

// K=16 MFMA: D = A(16x16) * B(16x16) + C. B-operand layout (col=l15, k=g*4+j)
// matches the 16x16 C/D layout (col=l15, row=g*4+r) -> S^T regs feed PV directly.
__device__ __forceinline__ f32x4 mfma_k16(bf16x4 a, bf16x4 b, f32x4 c){
#if __has_builtin(__builtin_amdgcn_mfma_f32_16x16x16_bf16)
  return __builtin_amdgcn_mfma_f32_16x16x16_bf16(a, b, c, 0, 0, 0);
#elif __has_builtin(__builtin_amdgcn_mfma_f32_16x16x16bf16_1k)
  s16x4 ai, bi;
  __builtin_memcpy(&ai, &a, 8);
  __builtin_memcpy(&bi, &b, 8);
  return __builtin_amdgcn_mfma_f32_16x16x16bf16_1k(ai, bi, c, 0, 0, 0);
#else
  asm("v_mfma_f32_16x16x16_bf16 %0, %1, %2, %0" : "+v"(c) : "v"(a), "v"(b));
  return c;
#endif
}

__device__ __forceinline__ bf16x4 pack4(float a, float b, float c, float d){
  bf16x4 r; r[0]=(__bf16)a; r[1]=(__bf16)b; r[2]=(__bf16)c; r[3]=(__bf16)d; return r;
}

__device__ __forceinline__ void gl2lds16(const void* g, void* l){
  __builtin_amdgcn_global_load_lds(
      (const __attribute__((address_space(1))) unsigned int*)g,
      (__attribute__((address_space(3))) unsigned int*)l, 16, 0, 0);
}

// Read one bf16x8 MFMA fragment from a [rows][64-elem] XOR-swizzled LDS tile.
// Physical granule slot = logical_granule ^ (row & 7)  (16B granules, 8/row).
__device__ __forceinline__ bf16x8 ldsfrag(const u16* base, int row, int gr){
  return *(const bf16x8*)(base + row * 64 + ((gr ^ (row & 7)) << 3));
}
// b64 variant: granule gr, half h (0/1 -> 4-elem offset).
__device__ __forceinline__ bf16x4 ldsfrag64(const u16* base, int row, int gr, int h){
  return *(const bf16x4*)(base + row * 64 + ((gr ^ (row & 7)) << 3) + (h << 2));
}

// XCD-locality remap (T1): hw round-robins consecutive flat ids across 8 XCDs.
// Remap so each XCD walks tile-x fastest within its OWN contiguous y-panels ->
// blocks sharing an A-panel (same y) co-locate on one XCD and hit its L2.
// Requires nY % 8 == 0. Bijective. [verified r12: k_proj FETCH 210->59 MB]
__device__ __forceinline__ void xcd_remap(int& tx, int& ty){
  const int nX = (int)gridDim.x, nY = (int)gridDim.y;
  const int flat = (int)blockIdx.x + nX * (int)blockIdx.y;
  const int xcd = flat & 7, j = flat >> 3;
  tx = j % nX;
  ty = xcd * (nY >> 3) + j / nX;
}

// ---------------------------------------------------------------------------
// GEMM core: C[M,N] = A[M,K] @ Bt[N,K]^T, bf16 in, fp32 accumulate.
// Block = 256 thr (4 waves, 2x2), tile 128 x BN, BK=64, double-buffered LDS
// via async global_load_lds (NO reg-staging: r10-12 showed the f32 reg-staged
// path is latency-bound on load->ds_write->barrier, 75us vs ~30us).
// XCD-swizzled tiles.
// mode 0: bf16 C [row*N+col], scaled by oscale
// mode 1: bf16 C transposed-V layout:  [((b*16+h)*64+e)*2048 + l], packed x4
// mode 4: bf16 C + bias[col]
// ---------------------------------------------------------------------------
template<int BN>
__device__ __forceinline__ void gemm_core(const u16* __restrict__ A,
                                          const u16* __restrict__ Bt,
                                          int N, int K, int mode,
                                          void* __restrict__ Cout,
                                          const float* __restrict__ bias,
                                          float oscale)
{
  constexpr int NF = BN / 32;          // B-frags per wave (wave covers BN/2 cols)
  __shared__ u16 Al[2][128 * 64];
  __shared__ u16 Bl[2][BN * 64];
  const int tid  = threadIdx.x;
  const int lane = tid & 63;
  const int w    = tid >> 6;
  const int wr   = w >> 1, wc = w & 1;
  const int l15  = lane & 15, g = lane >> 4;
  int tx, ty;
  xcd_remap(tx, ty);
  const int rowBase = ty << 7;
  const int colBase = tx * BN;

  // staging: thread t handles row (i*32 + t/8), granule t%8, pre-swizzled col
  const int srow = tid >> 3;                          // 0..31
  const int swz  = ((tid & 7) ^ (srow & 7)) << 3;     // element offset in row
  const u16* Ag = A  + (size_t)(rowBase + srow) * K + swz;
  const u16* Bg = Bt + (size_t)(colBase + srow) * K + swz;

  f32x4 acc[4][NF];
#pragma unroll
  for (int m = 0; m < 4; ++m)
#pragma unroll
    for (int n = 0; n < NF; ++n) acc[m][n] = f32x4{0.f, 0.f, 0.f, 0.f};

  auto stage = [&](int buf, int k0) {
#pragma unroll
    for (int i = 0; i < 4; ++i)
      gl2lds16(Ag + (size_t)(i * 32) * K + k0, Al[buf] + i * 2048 + w * 512);
#pragma unroll
    for (int i = 0; i < BN / 32; ++i)
      gl2lds16(Bg + (size_t)(i * 32) * K + k0, Bl[buf] + i * 2048 + w * 512);
  };
  auto compute = [&](int buf) {
    __builtin_amdgcn_s_setprio(1);
#pragma unroll
    for (int kk = 0; kk < 2; ++kk) {
      bf16x8 af[4], bfr[NF];
#pragma unroll
      for (int m = 0; m < 4; ++m) af[m]  = ldsfrag(Al[buf], wr * 64 + m * 16 + l15, kk * 4 + g);
#pragma unroll
      for (int n = 0; n < NF; ++n) bfr[n] = ldsfrag(Bl[buf], wc * (BN/2) + n * 16 + l15, kk * 4 + g);
#pragma unroll
      for (int m = 0; m < 4; ++m)
#pragma unroll
        for (int n = 0; n < NF; ++n)
          acc[m][n] = MFMA16(af[m], bfr[n], acc[m][n]);
    }
    __builtin_amdgcn_s_setprio(0);
  };

  stage(0, 0);
  __syncthreads();
  int cur = 0;
  for (int k0 = 0; k0 < K; k0 += 64) {
    if (k0 + 64 < K) stage(cur ^ 1, k0 + 64);
    compute(cur);
    __syncthreads();
    cur ^= 1;
  }

#pragma unroll
  for (int m = 0; m < 4; ++m) {
#pragma unroll
    for (int n = 0; n < NF; ++n) {
      const int row0 = rowBase + wr * 64 + m * 16 + g * 4;  // rows row0..row0+3
      const int col  = colBase + wc * (BN/2) + n * 16 + l15;
      if (mode == 1) {
        // rows = (b,l) with l consecutive over r; col = (h,e). Pack 4 l's.
        const int b = row0 >> 11, l = row0 & 2047;
        const int h = col >> 6,  e = col & 63;
        *(bf16x4*)((u16*)Cout + ((size_t)((((b << 4) + h) << 6) | e) << 11) + l) =
            pack4(acc[m][n][0], acc[m][n][1], acc[m][n][2], acc[m][n][3]);
      } else {
        const float bb = (mode == 4) ? bias[col] : 0.f;
#pragma unroll
        for (int r = 0; r < 4; ++r) {
          const int row = row0 + r;
          const float v = acc[m][n][r];
          if (mode == 0) {
            *(__bf16*)((u16*)Cout + (size_t)row * N + col) = (__bf16)(v * oscale);
          } else {
            *(__bf16*)((u16*)Cout + (size_t)row * N + col) = (__bf16)(v + bb);
          }
        }
      }
    }
  }
}

// log2(e)/8: folded into Q so attention softmax runs in exp2 domain.
#define QSCALE 0.18033688011112042f

__global__ __launch_bounds__(256) void k_proj(
    const u16* __restrict__ qb, const u16* __restrict__ kb, const u16* __restrict__ vb,
    const u16* __restrict__ wq, const u16* __restrict__ wk, const u16* __restrict__ wv,
    u16* __restrict__ Qp, u16* __restrict__ Kp, u16* __restrict__ Vt)
{
  const int z = blockIdx.z;
  const u16* A = (z == 0) ? qb : (z == 1) ? kb : vb;
  const u16* B = (z == 0) ? wq : (z == 1) ? wk : wv;
  void* C = (z == 0) ? (void*)Qp : (z == 1) ? (void*)Kp : (void*)Vt;
  gemm_core<64>(A, B, 1024, 1024, (z == 2) ? 1 : 0, C, nullptr, (z == 0) ? QSCALE : 1.0f);
}

__global__ __launch_bounds__(256) void k_gemm_o(const u16* __restrict__ A,
                                                const u16* __restrict__ B,
                                                u16* __restrict__ C)
{ gemm_core<64>(A, B, 1024, 1024, 0, (void*)C, nullptr, 1.0f); }

__global__ __launch_bounds__(256) void k_gemm_fc(const u16* __restrict__ A,
                                                 const u16* __restrict__ B,
                                                 u16* __restrict__ C,
                                                 const float* __restrict__ bias)
{ gemm_core<64>(A, B, 1024, 1024, 4, (void*)C, bias, 1.0f); }

// ---------------------------------------------------------------------------
// Flash attention v6c, split-KV + register-fed PV (no P LDS), bf16 partials,
// XCD-swizzled tiles (blocks sharing a head's K/V co-locate on one XCD):
// grid (L/128, B*H, 2), 256 thr = 4 waves, each wave owns 32 q-rows (2 groups).
// S^T = mfma_16x16x32(K, Q): lane (l15,g) holds q=l15, k=f*16+g*4+r.
// P_f = pack4(exp2(s[f])) is EXACTLY the B-operand of mfma_16x16x16 for
// k-block f -> O^T[fe] += mfma_k16(V^T[fe][f], P_f).
// Static-max softmax; exact split combine O = (O0+O1)/(d0+d1).
// ---------------------------------------------------------------------------
__global__ __launch_bounds__(256, 4) void k_attn(const u16* __restrict__ Qp,
                                                 const u16* __restrict__ Kp,
                                                 const u16* __restrict__ Vt,
                                                 u16* __restrict__ Opart,
                                                 float* __restrict__ dpart)
{
  __shared__ u16 Klds[2][64 * 64];    // 16 KB
  __shared__ u16 Vlds[2][64 * 64];    // 16 KB

  const int tid = threadIdx.x, lane = tid & 63, w = tid >> 6;
  const int l15 = lane & 15, g = lane >> 4;
  int tx, ty;
  xcd_remap(tx, ty);                  // tx = q-tile, ty = bh (panels share K/V)
  const int bh = ty, b = bh >> 4, h = bh & 15;
  const int q0 = tx << 7;
  const int half = blockIdx.z;
  const int kvbase = half << 10;      // 0 or 1024

  // Q fragments (B-operand of QK): lane needs Q[q][e = kk*32 + g*8 ..+7]
  bf16x8 bq[2][2];
#pragma unroll
  for (int u = 0; u < 2; ++u) {
    const u16* Qr = Qp + (((size_t)((b << 11) + q0 + (w << 5) + (u << 4) + l15)) << 10)
                  + (h << 6) + (g << 3);
    bq[u][0] = *(const bf16x8*)(Qr);
    bq[u][1] = *(const bf16x8*)(Qr + 32);
  }

  const f32x4 zero4 = {0.f, 0.f, 0.f, 0.f};
  f32x4 o0[4], o1[4];
#pragma unroll
  for (int f = 0; f < 4; ++f) { o0[f] = zero4; o1[f] = zero4; }
  float ds0 = 0.f, ds1 = 0.f;

  const int srow = tid >> 3;
  const int swz  = ((tid & 7) ^ (srow & 7)) << 3;
  const u16* Kg = Kp + (((size_t)((b << 11) + kvbase + srow)) << 10) + (h << 6) + swz;
  const u16* Vg = Vt + (((size_t)((bh << 6) + srow)) << 11) + kvbase + swz;

  auto stage = [&](int buf, int j0) {
#pragma unroll
    for (int i = 0; i < 2; ++i) {
      gl2lds16(Kg + ((size_t)(j0 + i * 32) << 10), Klds[buf] + i * 2048 + w * 512);
      gl2lds16(Vg + ((size_t)(i * 32) << 11) + j0, Vlds[buf] + i * 2048 + w * 512);
    }
  };

  stage(0, 0);
  __syncthreads();
  int cur = 0;

  for (int j0 = 0; j0 < 1024; j0 += 64) {
    if (j0 + 64 < 1024) stage(cur ^ 1, j0 + 64);

    // S^T = K Q^T (log2 domain; scale pre-folded into Q). K frags shared by
    // both q-groups; per-f staging keeps register pressure low.
    f32x4 s0[4], s1[4];
    __builtin_amdgcn_s_setprio(1);
#pragma unroll
    for (int f = 0; f < 4; ++f) {
      const bf16x8 ka = ldsfrag(Klds[cur], f * 16 + l15, g);
      const bf16x8 kb = ldsfrag(Klds[cur], f * 16 + l15, 4 + g);
      s0[f] = MFMA16(ka, bq[0][0], zero4);
      s0[f] = MFMA16(kb, bq[0][1], s0[f]);
      s1[f] = MFMA16(ka, bq[1][0], zero4);
      s1[f] = MFMA16(kb, bq[1][1], s1[f]);
    }
    __builtin_amdgcn_s_setprio(0);

    // P = exp2(S) packed straight into PV B-operand fragments (in-register)
    bf16x4 p0[4], p1[4];
#pragma unroll
    for (int f = 0; f < 4; ++f) {
      const float a0 = __builtin_amdgcn_exp2f(s0[f][0]);
      const float a1 = __builtin_amdgcn_exp2f(s0[f][1]);
      const float a2 = __builtin_amdgcn_exp2f(s0[f][2]);
      const float a3 = __builtin_amdgcn_exp2f(s0[f][3]);
      ds0 += (a0 + a1) + (a2 + a3);
      p0[f] = pack4(a0, a1, a2, a3);
      const float c0 = __builtin_amdgcn_exp2f(s1[f][0]);
      const float c1 = __builtin_amdgcn_exp2f(s1[f][1]);
      const float c2 = __builtin_amdgcn_exp2f(s1[f][2]);
      const float c3 = __builtin_amdgcn_exp2f(s1[f][3]);
      ds1 += (c0 + c1) + (c2 + c3);
      p1[f] = pack4(c0, c1, c2, c3);
    }

    // O^T[fe] += V^T[fe][f] * P[f]  (A = b64 V frag, B = in-register P)
    __builtin_amdgcn_s_setprio(1);
#pragma unroll
    for (int fe = 0; fe < 4; ++fe) {
#pragma unroll
      for (int f = 0; f < 4; ++f) {
        const bf16x4 va = ldsfrag64(Vlds[cur], fe * 16 + l15, 2 * f + (g >> 1), g & 1);
        o0[fe] = mfma_k16(va, p0[f], o0[fe]);
        o1[fe] = mfma_k16(va, p1[f], o1[fe]);
      }
    }
    __builtin_amdgcn_s_setprio(0);
    __syncthreads();
    cur ^= 1;
  }

  // partial denominators: sum the 4 disjoint k-subsets held by the 4 g-groups
  ds0 += __shfl_xor(ds0, 16, 64);
  ds0 += __shfl_xor(ds0, 32, 64);
  ds1 += __shfl_xor(ds1, 16, 64);
  ds1 += __shfl_xor(ds1, 32, 64);

  const int brow0 = (b << 11) + q0 + (w << 5) + l15;   // row in [0, B*L)
  const int brow1 = brow0 + 16;
  u16* Op = Opart + ((size_t)half << 22);              // half * 4096*1024 elems
#pragma unroll
  for (int f = 0; f < 4; ++f) {
    *(bf16x4*)(Op + (((size_t)brow0) << 10) + (h << 6) + f * 16 + (g << 2)) =
        pack4(o0[f][0], o0[f][1], o0[f][2], o0[f][3]);
    *(bf16x4*)(Op + (((size_t)brow1) << 10) + (h << 6) + f * 16 + (g << 2)) =
        pack4(o1[f][0], o1[f][1], o1[f][2], o1[f][3]);
  }
  if (g == 0) {
    dpart[(half << 16) + (brow0 << 4) + h] = ds0;
    dpart[(half << 16) + (brow1 << 4) + h] = ds1;
  }
}

// ---------------------------------------------------------------------------
// split-KV combine: ctx = (O0 + O1) / (d0 + d1), bf16 in/out. 1 block per row.
// ---------------------------------------------------------------------------
__global__ __launch_bounds__(256) void k_combine(const u16* __restrict__ Opart,
                                                 const float* __restrict__ dpart,
                                                 u16* __restrict__ ctx)
{
  const int row = blockIdx.x, tid = threadIdx.x;
  const int h = tid >> 4;
  const float d = dpart[(row << 4) + h] + dpart[(1 << 16) + (row << 4) + h];
  const float inv = 1.0f / d;
  const bf16x4 p0 = ((const bf16x4*)(Opart + ((size_t)row << 10)))[tid];
  const bf16x4 p1 = ((const bf16x4*)(Opart + (1u << 22) + ((size_t)row << 10)))[tid];
  ((bf16x4*)(ctx + ((size_t)row << 10)))[tid] =
      pack4(((float)p0[0] + (float)p1[0]) * inv, ((float)p0[1] + (float)p1[1]) * inv,
            ((float)p0[2] + (float)p1[2]) * inv, ((float)p0[3] + (float)p1[3]) * inv);
}

// ---------------------------------------------------------------------------
// fused add + LayerNorm over D=1024 (one row per block, 256 thr x 4 elems)
// ln1: a bf16 + res f32 -> bf16 out.   ln2: a bf16 + res bf16 -> f32 out.
// ---------------------------------------------------------------------------
__device__ __forceinline__ void ln_stats(float4 t, int tid, float& mean, float& inv){
  float s = t.x + t.y + t.z + t.w;
  float q = t.x * t.x + t.y * t.y + t.z * t.z + t.w * t.w;
#pragma unroll
  for (int d = 1; d < 64; d <<= 1) {
    s += __shfl_xor(s, d, 64);
    q += __shfl_xor(q, d, 64);
  }
  __shared__ float ps[4], pq[4];
  const int w = tid >> 6;
  if ((tid & 63) == 0) { ps[w] = s; pq[w] = q; }
  __syncthreads();
  s = ps[0] + ps[1] + ps[2] + ps[3];
  q = pq[0] + pq[1] + pq[2] + pq[3];
  mean = s * (1.0f / 1024.0f);
  const float var = q * (1.0f / 1024.0f) - mean * mean;
  inv = rsqrtf(var + 1e-5f);
}

__global__ __launch_bounds__(256) void k_ln1(const u16* __restrict__ a,
                                             const float* __restrict__ res,
                                             u16* __restrict__ xb)
{
  const int row = blockIdx.x, tid = threadIdx.x;
  const size_t base = (size_t)row << 10;
  const bf16x4 av = ((const bf16x4*)(a + base))[tid];
  const float4 rr = ((const float4*)(res + base))[tid];
  float4 t;
  t.x = (float)av[0] + rr.x; t.y = (float)av[1] + rr.y;
  t.z = (float)av[2] + rr.z; t.w = (float)av[3] + rr.w;
  float mean, inv;
  ln_stats(t, tid, mean, inv);
  ((bf16x4*)(xb + base))[tid] = pack4((t.x - mean) * inv, (t.y - mean) * inv,
                                      (t.z - mean) * inv, (t.w - mean) * inv);
}

__global__ __launch_bounds__(256) void k_ln2(const u16* __restrict__ a,
                                             const u16* __restrict__ res,
                                             float* __restrict__ out)
{
  const int row = blockIdx.x, tid = threadIdx.x;
  const size_t base = (size_t)row << 10;
  const bf16x4 av = ((const bf16x4*)(a + base))[tid];
  const bf16x4 rv = ((const bf16x4*)(res + base))[tid];
  float4 t;
  t.x = (float)av[0] + (float)rv[0]; t.y = (float)av[1] + (float)rv[1];
  t.z = (float)av[2] + (float)rv[2]; t.w = (float)av[3] + (float)rv[3];
  float mean, inv;
  ln_stats(t, tid, mean, inv);
  float4 o;
  o.x = (t.x - mean) * inv; o.y = (t.y - mean) * inv;
  o.z = (t.z - mean) * inv; o.w = (t.w - mean) * inv;
  ((float4*)(out + base))[tid] = o;
}

// merged fp32 -> bf16 converter: z=0..2 inputs (4096 blocks), z=3..7 weights
// (1024 blocks; extra blocks exit).
__global__ __launch_bounds__(256) void k_cvt8(
    const float* __restrict__ a0, const float* __restrict__ a1,
    const float* __restrict__ a2, const float* __restrict__ a3,
    const float* __restrict__ a4, const float* __restrict__ a5,
    const float* __restrict__ a6, const float* __restrict__ a7,
    u16* __restrict__ o0, u16* __restrict__ o1, u16* __restrict__ o2,
    u16* __restrict__ o3, u16* __restrict__ o4, u16* __restrict__ o5,
    u16* __restrict__ o6, u16* __restrict__ o7)
{
  const int z = blockIdx.y;
  if (z >= 3 && blockIdx.x >= 1024) return;
  const float* src = (z == 0) ? a0 : (z == 1) ? a1 : (z == 2) ? a2 : (z == 3) ? a3
                   : (z == 4) ? a4 : (z == 5) ? a5 : (z == 6) ? a6 : a7;
  u16* dst = (z == 0) ? o0 : (z == 1) ? o1 : (z == 2) ? o2 : (z == 3) ? o3
           : (z == 4) ? o4 : (z == 5) ? o5 : (z == 6) ? o6 : o7;
  const int i = blockIdx.x * 256 + threadIdx.x;
  const float4 t = ((const float4*)src)[i];
  ((bf16x4*)dst)[i] = pack4(t.x, t.y, t.z, t.w);
}

extern "C" void kernel_launch(void* const* d_in, const int* in_sizes, int n_in,
                              void* d_out, int out_size, void* d_ws, size_t ws_size,
                              hipStream_t stream)
{
  (void)in_sizes; (void)n_in; (void)out_size; (void)ws_size;
  const float* query = (const float*)d_in[0];
  const float* key   = (const float*)d_in[1];
  const float* value = (const float*)d_in[2];
  const float* W_Q   = (const float*)d_in[3];
  const float* W_K   = (const float*)d_in[4];
  const float* W_V   = (const float*)d_in[5];
  const float* W_O   = (const float*)d_in[6];
  const float* fc_w  = (const float*)d_in[7];
  const float* fc_b  = (const float*)d_in[8];
  float* out = (float*)d_out;
  char* ws = (char*)d_ws;

  // workspace layout (bytes)
  u16*   qb    = (u16*)(ws + 0);          //  8.39 MB (reused later by yb)
  u16*   kb    = (u16*)(ws + 8388608);
  u16*   vb    = (u16*)(ws + 16777216);   //  8.39 MB (reused later by xb)
  u16*   wq    = (u16*)(ws + 25165824);
  u16*   wk    = (u16*)(ws + 27262976);
  u16*   wv    = (u16*)(ws + 29360128);
  u16*   wo    = (u16*)(ws + 31457280);
  u16*   fw    = (u16*)(ws + 33554432);
  u16*   Qp    = (u16*)(ws + 35651584);
  u16*   Kp    = (u16*)(ws + 44040192);
  u16*   Vt    = (u16*)(ws + 52428800);
  u16*   ctx   = (u16*)(ws + 60817408);
  u16*   Opart = (u16*)(ws + 69206016);   // 16.78 MB (2 x 8.39 bf16)
  float* dpart = (float*)(ws + 85983232); //  0.52 MB ; total ~86.5 MB
  u16*   attnb = (u16*)(ws + 69206016);   // aliases Opart (temporally disjoint)
  u16*   xb    = vb;                      // reuse (vb dead after projections)
  u16*   yb    = qb;                      // reuse (qb dead after projections)

  k_cvt8<<<dim3(4096, 8), 256, 0, stream>>>(query, key, value, W_Q, W_K, W_V, W_O, fc_w,
                                            qb, kb, vb, wq, wk, wv, wo, fw);
  k_proj<<<dim3(16, 32, 3), 256, 0, stream>>>(qb, kb, vb, wq, wk, wv, Qp, Kp, Vt);
  k_attn<<<dim3(16, 32, 2), 256, 0, stream>>>(Qp, Kp, Vt, Opart, dpart);
  k_combine<<<dim3(4096), 256, 0, stream>>>(Opart, dpart, ctx);
  k_gemm_o<<<dim3(16, 32), 256, 0, stream>>>(ctx, wo, attnb);
  k_ln1<<<dim3(4096), 256, 0, stream>>>(attnb, query, xb);
  k_gemm_fc<<<dim3(16, 32), 256, 0, stream>>>(xb, fw, yb, fc_b);
  k_ln2<<<dim3(4096), 256, 0, stream>>>(yb, xb, out);
}